// Round 1
// baseline (609.217 us; speedup 1.0000x reference)
//
#include <hip/hip_runtime.h>
#include <cstdint>
#include <cstddef>

#define DN 128
#define NND 50000
#define NED 512000

typedef __attribute__((ext_vector_type(8))) short bf8;
typedef __attribute__((ext_vector_type(4))) float f4;

__device__ __forceinline__ unsigned short f2bf(float f){
  union { float f; unsigned int u; } c; c.f = f;
  unsigned int r = c.u + 0x7fffu + ((c.u >> 16) & 1u);
  return (unsigned short)(r >> 16);
}
__device__ __forceinline__ float bf2f(unsigned short u){
  union { unsigned int u; float f; } c; c.u = ((unsigned int)u) << 16;
  return c.f;
}
// mish(x) = x*tanh(softplus(x)) = x*(u^2-1)/(u^2+1), u = 1+exp(x)
__device__ __forceinline__ float mishf(float x){
  float e = __expf(x);
  float u = 1.f + e;
  float u2 = u * u;
  float t = (u2 - 1.f) / (u2 + 1.f);
  return x * ((x > 20.f) ? 1.f : t);
}

#define MFMA16(a, b, c) __builtin_amdgcn_mfma_f32_16x16x32_bf16((a), (b), (c), 0, 0, 0)

// LDS fragment read: row-major [rows][K] bf16 with (row&7)<<4 byte XOR swizzle.
__device__ __forceinline__ bf8 lds_frag(const unsigned short* base, int row, int rowStrideB, int kElem){
  int byte = row * rowStrideB + kElem * 2;
  byte ^= (row & 7) << 4;
  return *(const bf8*)((const char*)base + byte);
}
// Global weight fragment: W^T stored [Nout][K] bf16, plain row-major.
__device__ __forceinline__ bf8 gfrag(const unsigned short* W, int n, int K, int kElem){
  return *(const bf8*)(W + (size_t)n * K + kElem);
}

template<int OUT_BF16>
__device__ __forceinline__ void store_tile(void* outp, int nrows, int r0,
                                           int wr, int wc, int g, int s,
                                           const f4 (&A)[2][4]){
#pragma unroll
  for (int rt = 0; rt < 2; ++rt)
#pragma unroll
    for (int ct = 0; ct < 4; ++ct)
#pragma unroll
      for (int reg = 0; reg < 4; ++reg){
        int row = r0 + wr*32 + rt*16 + g*4 + reg;
        if (row < nrows){
          int col = wc*64 + ct*16 + s;
          float v = A[rt][ct][reg];
          if constexpr (OUT_BF16 != 0)
            ((unsigned short*)outp)[(size_t)row*DN + col] = f2bf(v);
          else
            ((float*)outp)[(size_t)row*DN + col] = v;
        }
      }
}

// out = [mish( LN?( X@W1 + b1 ) )] [@ W2 + b2]?   for 64-row blocks
template<int HAS_LN, int HAS_G2, int OUT_BF16>
__global__ __launch_bounds__(256, 2)
void node_chain(const float* __restrict__ X,
                const unsigned short* __restrict__ W1T,
                const float* __restrict__ b1,
                const float* __restrict__ gam,
                const float* __restrict__ bet,
                const unsigned short* __restrict__ W2T,
                const float* __restrict__ b2,
                void* __restrict__ outp, int nrows)
{
  __shared__ unsigned short Ash[64 * DN];
  __shared__ unsigned short Tsh[64 * DN];
  __shared__ float rowsum[64][2];
  __shared__ float rowsq[64][2];

  const int tid = threadIdx.x;
  const int r0 = blockIdx.x * 64;

  { // stage X rows -> bf16 swizzled LDS
    int r = tid >> 2, c4 = tid & 3;
    int grow = r0 + r; if (grow >= nrows) grow = nrows - 1;
    const f4* sp = (const f4*)(X + (size_t)grow * DN + c4 * 32);
#pragma unroll
    for (int j = 0; j < 4; ++j){
      f4 v0 = sp[2*j], v1 = sp[2*j+1];
      bf8 o;
#pragma unroll
      for (int q = 0; q < 4; ++q){ o[q] = (short)f2bf(v0[q]); o[4+q] = (short)f2bf(v1[q]); }
      int byte = r*256 + c4*64 + j*16; byte ^= (r & 7) << 4;
      *(bf8*)((char*)Ash + byte) = o;
    }
  }
  __syncthreads();

  const int lane = tid & 63, w = tid >> 6;
  const int wr = w >> 1, wc = w & 1;
  const int g = lane >> 4, s = lane & 15;

  float b1v[4], gv[4], bev[4];
#pragma unroll
  for (int ct = 0; ct < 4; ++ct){
    int n = wc*64 + ct*16 + s;
    b1v[ct] = b1[n];
    if constexpr (HAS_LN != 0){ gv[ct] = gam[n]; bev[ct] = bet[n]; }
  }

  f4 acc[2][4];
#pragma unroll
  for (int rt = 0; rt < 2; ++rt)
#pragma unroll
    for (int ct = 0; ct < 4; ++ct){ f4 t = {b1v[ct], b1v[ct], b1v[ct], b1v[ct]}; acc[rt][ct] = t; }

  bf8 a[2][4];
#pragma unroll
  for (int rt = 0; rt < 2; ++rt)
#pragma unroll
    for (int kk = 0; kk < 4; ++kk)
      a[rt][kk] = lds_frag(Ash, wr*32 + rt*16 + s, 256, kk*32 + g*8);

#pragma unroll
  for (int ct = 0; ct < 4; ++ct){
    int n = wc*64 + ct*16 + s;
#pragma unroll
    for (int kk = 0; kk < 4; ++kk){
      bf8 b = gfrag(W1T, n, DN, kk*32 + g*8);
      acc[0][ct] = MFMA16(a[0][kk], b, acc[0][ct]);
      acc[1][ct] = MFMA16(a[1][kk], b, acc[1][ct]);
    }
  }

  if constexpr (HAS_LN != 0){
#pragma unroll
    for (int rt = 0; rt < 2; ++rt)
#pragma unroll
      for (int reg = 0; reg < 4; ++reg){
        float sm = acc[rt][0][reg] + acc[rt][1][reg] + acc[rt][2][reg] + acc[rt][3][reg];
        float sq = acc[rt][0][reg]*acc[rt][0][reg] + acc[rt][1][reg]*acc[rt][1][reg]
                 + acc[rt][2][reg]*acc[rt][2][reg] + acc[rt][3][reg]*acc[rt][3][reg];
#pragma unroll
        for (int m = 1; m < 16; m <<= 1){ sm += __shfl_xor(sm, m, 64); sq += __shfl_xor(sq, m, 64); }
        if (s == 0){
          int row = wr*32 + rt*16 + g*4 + reg;
          rowsum[row][wc] = sm; rowsq[row][wc] = sq;
        }
      }
    __syncthreads();
#pragma unroll
    for (int rt = 0; rt < 2; ++rt)
#pragma unroll
      for (int reg = 0; reg < 4; ++reg){
        int row = wr*32 + rt*16 + g*4 + reg;
        float sm = rowsum[row][0] + rowsum[row][1];
        float sq = rowsq[row][0] + rowsq[row][1];
        float mu = sm * (1.f/128.f);
        float var = sq * (1.f/128.f) - mu*mu;
        float rs = rsqrtf(var + 1e-5f);
#pragma unroll
        for (int ct = 0; ct < 4; ++ct)
          acc[rt][ct][reg] = (acc[rt][ct][reg] - mu) * rs * gv[ct] + bev[ct];
      }
  }

#pragma unroll
  for (int rt = 0; rt < 2; ++rt)
#pragma unroll
    for (int ct = 0; ct < 4; ++ct)
#pragma unroll
      for (int reg = 0; reg < 4; ++reg)
        acc[rt][ct][reg] = mishf(acc[rt][ct][reg]);

  if constexpr (HAS_G2 != 0){
#pragma unroll
    for (int rt = 0; rt < 2; ++rt)
#pragma unroll
      for (int ct = 0; ct < 4; ++ct)
#pragma unroll
        for (int reg = 0; reg < 4; ++reg){
          int row = wr*32 + rt*16 + g*4 + reg;
          int col = wc*64 + ct*16 + s;
          int byte = row*256 + col*2; byte ^= (row & 7) << 4;
          *(unsigned short*)((char*)Tsh + byte) = f2bf(acc[rt][ct][reg]);
        }
    __syncthreads();

    float b2v[4];
#pragma unroll
    for (int ct = 0; ct < 4; ++ct) b2v[ct] = b2 ? b2[wc*64 + ct*16 + s] : 0.f;
    f4 acc2[2][4];
#pragma unroll
    for (int rt = 0; rt < 2; ++rt)
#pragma unroll
      for (int ct = 0; ct < 4; ++ct){ f4 t = {b2v[ct], b2v[ct], b2v[ct], b2v[ct]}; acc2[rt][ct] = t; }
    bf8 a2[2][4];
#pragma unroll
    for (int rt = 0; rt < 2; ++rt)
#pragma unroll
      for (int kk = 0; kk < 4; ++kk)
        a2[rt][kk] = lds_frag(Tsh, wr*32 + rt*16 + s, 256, kk*32 + g*8);
#pragma unroll
    for (int ct = 0; ct < 4; ++ct){
      int n = wc*64 + ct*16 + s;
#pragma unroll
      for (int kk = 0; kk < 4; ++kk){
        bf8 b = gfrag(W2T, n, DN, kk*32 + g*8);
        acc2[0][ct] = MFMA16(a2[0][kk], b, acc2[0][ct]);
        acc2[1][ct] = MFMA16(a2[1][kk], b, acc2[1][ct]);
      }
    }
    store_tile<OUT_BF16>(outp, nrows, r0, wr, wc, g, s, acc2);
  } else {
    store_tile<OUT_BF16>(outp, nrows, r0, wr, wc, g, s, acc);
  }
}

// Edge pass: rel -> GEMM(Ww1)+LN+mish -> GEMM(Ww2) -> exp -> scatter + colsum
__global__ __launch_bounds__(256, 2)
void edge_kernel(const unsigned short* __restrict__ qtab,
                 const unsigned short* __restrict__ ktab,
                 const unsigned short* __restrict__ mtab,
                 const unsigned short* __restrict__ btab,
                 const unsigned short* __restrict__ W1T,
                 const unsigned short* __restrict__ W2T,
                 const float* __restrict__ bw1,
                 const float* __restrict__ gwp,
                 const float* __restrict__ bewp,
                 const float* __restrict__ bw2,
                 const int* __restrict__ srcI,
                 const int* __restrict__ dstI,
                 float* __restrict__ hneigh,
                 float* __restrict__ colsum)
{
  __shared__ unsigned short Ash[64 * DN];
  __shared__ unsigned short Tsh[64 * DN];
  __shared__ float rowsum[64][2];
  __shared__ float rowsq[64][2];
  __shared__ int dsh[64];
  __shared__ float csh[DN];

  const int tid = threadIdx.x;
  const int e0 = blockIdx.x * 64;
  const int lane = tid & 63, w = tid >> 6;
  const int wr = w >> 1, wc = w & 1;
  const int g = lane >> 4, s = lane & 15;

  if (tid < 64) dsh[tid] = dstI[e0 + tid];
  if (tid < DN) csh[tid] = 0.f;

  // register-pinned weight fragments (per wave)
  bf8 B1[4][4], B2[4][4];
  float b1v[4], gv[4], bev[4], b2v[4];
#pragma unroll
  for (int ct = 0; ct < 4; ++ct){
    int n = wc*64 + ct*16 + s;
#pragma unroll
    for (int kk = 0; kk < 4; ++kk){
      B1[ct][kk] = gfrag(W1T, n, DN, kk*32 + g*8);
      B2[ct][kk] = gfrag(W2T, n, DN, kk*32 + g*8);
    }
    b1v[ct] = bw1[n]; gv[ct] = gwp[n]; bev[ct] = bewp[n]; b2v[ct] = bw2[n];
  }

  { // gather + rel construction -> Ash
    int r = tid >> 2, c4 = tid & 3;
    int e = e0 + r;
    int sn = srcI[e], dn = dstI[e];
    const bf8* qp = (const bf8*)(qtab + (size_t)sn * DN + c4 * 32);
    const bf8* kp = (const bf8*)(ktab + (size_t)dn * DN + c4 * 32);
    const bf8* mp = (const bf8*)(mtab + (size_t)dn * DN + c4 * 32);
    const bf8* bp = (const bf8*)(btab + (size_t)dn * DN + c4 * 32);
    float rel[32]; float ss = 0.f;
#pragma unroll
    for (int j = 0; j < 4; ++j){
      bf8 qv = qp[j], kv = kp[j];
#pragma unroll
      for (int q = 0; q < 8; ++q){
        float d = bf2f((unsigned short)qv[q]) - bf2f((unsigned short)kv[q]);
        rel[j*8+q] = d; ss += d * d;
      }
    }
    ss += __shfl_xor(ss, 1, 64);
    ss += __shfl_xor(ss, 2, 64);
    float rinv = rsqrtf(ss + 1e-8f);
#pragma unroll
    for (int j = 0; j < 4; ++j){
      bf8 mv = mp[j], bv = bp[j];
      bf8 o;
#pragma unroll
      for (int q = 0; q < 8; ++q){
        float v = rel[j*8+q] * rinv * bf2f((unsigned short)mv[q]) + bf2f((unsigned short)bv[q]);
        o[q] = (short)f2bf(v);
      }
      int byte = r*256 + c4*64 + j*16; byte ^= (r & 7) << 4;
      *(bf8*)((char*)Ash + byte) = o;
    }
  }
  __syncthreads();

  // GEMM1
  f4 acc[2][4];
#pragma unroll
  for (int rt = 0; rt < 2; ++rt)
#pragma unroll
    for (int ct = 0; ct < 4; ++ct){ f4 t = {b1v[ct], b1v[ct], b1v[ct], b1v[ct]}; acc[rt][ct] = t; }
  bf8 a[2][4];
#pragma unroll
  for (int rt = 0; rt < 2; ++rt)
#pragma unroll
    for (int kk = 0; kk < 4; ++kk)
      a[rt][kk] = lds_frag(Ash, wr*32 + rt*16 + s, 256, kk*32 + g*8);
#pragma unroll
  for (int ct = 0; ct < 4; ++ct)
#pragma unroll
    for (int kk = 0; kk < 4; ++kk){
      acc[0][ct] = MFMA16(a[0][kk], B1[ct][kk], acc[0][ct]);
      acc[1][ct] = MFMA16(a[1][kk], B1[ct][kk], acc[1][ct]);
    }

  // LN (cross-wave row stats)
#pragma unroll
  for (int rt = 0; rt < 2; ++rt)
#pragma unroll
    for (int reg = 0; reg < 4; ++reg){
      float sm = acc[rt][0][reg] + acc[rt][1][reg] + acc[rt][2][reg] + acc[rt][3][reg];
      float sq = acc[rt][0][reg]*acc[rt][0][reg] + acc[rt][1][reg]*acc[rt][1][reg]
               + acc[rt][2][reg]*acc[rt][2][reg] + acc[rt][3][reg]*acc[rt][3][reg];
#pragma unroll
      for (int m = 1; m < 16; m <<= 1){ sm += __shfl_xor(sm, m, 64); sq += __shfl_xor(sq, m, 64); }
      if (s == 0){
        int row = wr*32 + rt*16 + g*4 + reg;
        rowsum[row][wc] = sm; rowsq[row][wc] = sq;
      }
    }
  __syncthreads();
#pragma unroll
  for (int rt = 0; rt < 2; ++rt)
#pragma unroll
    for (int reg = 0; reg < 4; ++reg){
      int row = wr*32 + rt*16 + g*4 + reg;
      float sm = rowsum[row][0] + rowsum[row][1];
      float sq = rowsq[row][0] + rowsq[row][1];
      float mu = sm * (1.f/128.f);
      float var = sq * (1.f/128.f) - mu*mu;
      float rs = rsqrtf(var + 1e-5f);
#pragma unroll
      for (int ct = 0; ct < 4; ++ct)
        acc[rt][ct][reg] = mishf((acc[rt][ct][reg] - mu) * rs * gv[ct] + bev[ct]);
    }

  // write t -> Tsh
#pragma unroll
  for (int rt = 0; rt < 2; ++rt)
#pragma unroll
    for (int ct = 0; ct < 4; ++ct)
#pragma unroll
      for (int reg = 0; reg < 4; ++reg){
        int row = wr*32 + rt*16 + g*4 + reg;
        int col = wc*64 + ct*16 + s;
        int byte = row*256 + col*2; byte ^= (row & 7) << 4;
        *(unsigned short*)((char*)Tsh + byte) = f2bf(acc[rt][ct][reg]);
      }
  __syncthreads();

  // GEMM2 -> p = exp(w)
  f4 p[2][4];
#pragma unroll
  for (int rt = 0; rt < 2; ++rt)
#pragma unroll
    for (int ct = 0; ct < 4; ++ct){ f4 t = {b2v[ct], b2v[ct], b2v[ct], b2v[ct]}; p[rt][ct] = t; }
  bf8 a2[2][4];
#pragma unroll
  for (int rt = 0; rt < 2; ++rt)
#pragma unroll
    for (int kk = 0; kk < 4; ++kk)
      a2[rt][kk] = lds_frag(Tsh, wr*32 + rt*16 + s, 256, kk*32 + g*8);
#pragma unroll
  for (int ct = 0; ct < 4; ++ct)
#pragma unroll
    for (int kk = 0; kk < 4; ++kk){
      p[0][ct] = MFMA16(a2[0][kk], B2[ct][kk], p[0][ct]);
      p[1][ct] = MFMA16(a2[1][kk], B2[ct][kk], p[1][ct]);
    }
#pragma unroll
  for (int rt = 0; rt < 2; ++rt)
#pragma unroll
    for (int ct = 0; ct < 4; ++ct)
#pragma unroll
      for (int reg = 0; reg < 4; ++reg)
        p[rt][ct][reg] = __expf(p[rt][ct][reg]);

  // per-column partial sums (block-local then one global atomic per column)
#pragma unroll
  for (int ct = 0; ct < 4; ++ct){
    float cp = 0.f;
#pragma unroll
    for (int rt = 0; rt < 2; ++rt)
#pragma unroll
      for (int reg = 0; reg < 4; ++reg) cp += p[rt][ct][reg];
    cp += __shfl_xor(cp, 16, 64);
    cp += __shfl_xor(cp, 32, 64);
    if (g == 0) atomicAdd(&csh[wc*64 + ct*16 + s], cp);
  }

  // scatter-add exp(w) to h_neigh[dst]
#pragma unroll
  for (int rt = 0; rt < 2; ++rt)
#pragma unroll
    for (int reg = 0; reg < 4; ++reg){
      int rl = wr*32 + rt*16 + g*4 + reg;
      float* hp = hneigh + (size_t)dsh[rl] * DN;
#pragma unroll
      for (int ct = 0; ct < 4; ++ct)
        atomicAdd(hp + (wc*64 + ct*16 + s), p[rt][ct][reg]);
    }
  __syncthreads();
  if (tid < DN) atomicAdd(&colsum[tid], csh[tid]);
}

// h = mish(concat[node_feat, h_neigh/colsum] @ Wn1 + bn1) @ Wn2 + bn2
__global__ __launch_bounds__(256, 2)
void final_h(const float* __restrict__ nodef,
             const float* __restrict__ hneigh,
             const float* __restrict__ colsum,
             const unsigned short* __restrict__ Wn1T,
             const float* __restrict__ bn1,
             const unsigned short* __restrict__ Wn2T,
             const float* __restrict__ bn2,
             float* __restrict__ outh)
{
  __shared__ unsigned short Ash[64 * 256];
  __shared__ unsigned short Tsh[64 * DN];

  const int tid = threadIdx.x;
  const int r0 = blockIdx.x * 64;
  {
    int r = tid >> 2, c4 = tid & 3;
    int grow = r0 + r; if (grow >= NND) grow = NND - 1;
    const f4* np = (const f4*)(nodef + (size_t)grow * DN + c4 * 32);
    const f4* hp = (const f4*)(hneigh + (size_t)grow * DN + c4 * 32);
    const f4* cp = (const f4*)(colsum + c4 * 32);
#pragma unroll
    for (int j = 0; j < 4; ++j){
      f4 v0 = np[2*j], v1 = np[2*j+1];
      bf8 o;
#pragma unroll
      for (int q = 0; q < 4; ++q){ o[q] = (short)f2bf(v0[q]); o[4+q] = (short)f2bf(v1[q]); }
      int byte = r*512 + c4*64 + j*16; byte ^= (r & 7) << 4;
      *(bf8*)((char*)Ash + byte) = o;
      f4 h0 = hp[2*j], h1 = hp[2*j+1];
      f4 c0 = cp[2*j], c1 = cp[2*j+1];
      bf8 o2;
#pragma unroll
      for (int q = 0; q < 4; ++q){
        o2[q]   = (short)f2bf(__fdividef(h0[q], c0[q]));
        o2[4+q] = (short)f2bf(__fdividef(h1[q], c1[q]));
      }
      int byte2 = r*512 + 256 + c4*64 + j*16; byte2 ^= (r & 7) << 4;
      *(bf8*)((char*)Ash + byte2) = o2;
    }
  }
  __syncthreads();

  const int lane = tid & 63, w = tid >> 6;
  const int wr = w >> 1, wc = w & 1;
  const int g = lane >> 4, s = lane & 15;

  float b1v[4], b2v[4];
#pragma unroll
  for (int ct = 0; ct < 4; ++ct){ int n = wc*64 + ct*16 + s; b1v[ct] = bn1[n]; b2v[ct] = bn2[n]; }

  f4 acc[2][4];
#pragma unroll
  for (int rt = 0; rt < 2; ++rt)
#pragma unroll
    for (int ct = 0; ct < 4; ++ct){ f4 t = {b1v[ct], b1v[ct], b1v[ct], b1v[ct]}; acc[rt][ct] = t; }

  bf8 a[2][8];
#pragma unroll
  for (int rt = 0; rt < 2; ++rt)
#pragma unroll
    for (int kk = 0; kk < 8; ++kk)
      a[rt][kk] = lds_frag(Ash, wr*32 + rt*16 + s, 512, kk*32 + g*8);
#pragma unroll
  for (int ct = 0; ct < 4; ++ct){
    int n = wc*64 + ct*16 + s;
#pragma unroll
    for (int kk = 0; kk < 8; ++kk){
      bf8 b = gfrag(Wn1T, n, 256, kk*32 + g*8);
      acc[0][ct] = MFMA16(a[0][kk], b, acc[0][ct]);
      acc[1][ct] = MFMA16(a[1][kk], b, acc[1][ct]);
    }
  }

#pragma unroll
  for (int rt = 0; rt < 2; ++rt)
#pragma unroll
    for (int ct = 0; ct < 4; ++ct)
#pragma unroll
      for (int reg = 0; reg < 4; ++reg){
        int row = wr*32 + rt*16 + g*4 + reg;
        int col = wc*64 + ct*16 + s;
        int byte = row*256 + col*2; byte ^= (row & 7) << 4;
        *(unsigned short*)((char*)Tsh + byte) = f2bf(mishf(acc[rt][ct][reg]));
      }
  __syncthreads();

  f4 acc2[2][4];
#pragma unroll
  for (int rt = 0; rt < 2; ++rt)
#pragma unroll
    for (int ct = 0; ct < 4; ++ct){ f4 t = {b2v[ct], b2v[ct], b2v[ct], b2v[ct]}; acc2[rt][ct] = t; }
  bf8 a2[2][4];
#pragma unroll
  for (int rt = 0; rt < 2; ++rt)
#pragma unroll
    for (int kk = 0; kk < 4; ++kk)
      a2[rt][kk] = lds_frag(Tsh, wr*32 + rt*16 + s, 256, kk*32 + g*8);
#pragma unroll
  for (int ct = 0; ct < 4; ++ct){
    int n = wc*64 + ct*16 + s;
#pragma unroll
    for (int kk = 0; kk < 4; ++kk){
      bf8 b = gfrag(Wn2T, n, DN, kk*32 + g*8);
      acc2[0][ct] = MFMA16(a2[0][kk], b, acc2[0][ct]);
      acc2[1][ct] = MFMA16(a2[1][kk], b, acc2[1][ct]);
    }
  }
  store_tile<0>((void*)outh, NND, r0, wr, wc, g, s, acc2);
}

struct WPrepArgs {
  const float* w[12];
  unsigned short* wt[12];
  int K[12];
};

// W^T bf16: wt[n*K + k] = bf16(W[k*128 + n])
__global__ void prep_weights(WPrepArgs a){
  int widx = blockIdx.y;
  int K = a.K[widx];
  int idx = blockIdx.x * 256 + threadIdx.x;
  if (idx >= DN * K) return;
  int kshift = (K == 256) ? 8 : 7;
  int n = idx >> kshift;
  int k = idx & (K - 1);
  a.wt[widx][idx] = f2bf(a.w[widx][(size_t)k * DN + n]);
}

extern "C" void kernel_launch(void* const* d_in, const int* in_sizes, int n_in,
                              void* d_out, int out_size, void* d_ws, size_t ws_size,
                              hipStream_t stream) {
  const float* node_feat = (const float*)d_in[0];
  const float* coordf    = (const float*)d_in[1];
  const float* Wq  = (const float*)d_in[2];
  const float* bq  = (const float*)d_in[3];
  const float* gq  = (const float*)d_in[4];
  const float* beq = (const float*)d_in[5];
  const float* Wk  = (const float*)d_in[6];
  const float* bk  = (const float*)d_in[7];
  const float* gk  = (const float*)d_in[8];
  const float* bek = (const float*)d_in[9];
  const float* Wm1 = (const float*)d_in[10];
  const float* bm1 = (const float*)d_in[11];
  const float* gm  = (const float*)d_in[12];
  const float* bem = (const float*)d_in[13];
  const float* Wm2 = (const float*)d_in[14];
  const float* bm2 = (const float*)d_in[15];
  const float* Wb1 = (const float*)d_in[16];
  const float* bb1 = (const float*)d_in[17];
  const float* gb  = (const float*)d_in[18];
  const float* beb = (const float*)d_in[19];
  const float* Wb2 = (const float*)d_in[20];
  const float* bb2 = (const float*)d_in[21];
  const float* Ww1 = (const float*)d_in[22];
  const float* bw1 = (const float*)d_in[23];
  const float* gw  = (const float*)d_in[24];
  const float* bew = (const float*)d_in[25];
  const float* Ww2 = (const float*)d_in[26];
  const float* bw2 = (const float*)d_in[27];
  const float* Wn1 = (const float*)d_in[28];
  const float* bn1 = (const float*)d_in[29];
  const float* Wn2 = (const float*)d_in[30];
  const float* bn2 = (const float*)d_in[31];
  const float* Wc1 = (const float*)d_in[32];
  const float* bc1 = (const float*)d_in[33];
  const float* Wc2 = (const float*)d_in[34];
  const int* srcI  = (const int*)d_in[35];
  const int* dstI  = (const int*)d_in[36];

  char* ws = (char*)d_ws;
  const size_t SZ_TAB = (size_t)NND * DN * 2;        // bf16 node table
  unsigned short* qt = (unsigned short*)(ws + 0 * SZ_TAB);
  unsigned short* kt = (unsigned short*)(ws + 1 * SZ_TAB);
  unsigned short* mt = (unsigned short*)(ws + 2 * SZ_TAB);
  unsigned short* bt = (unsigned short*)(ws + 3 * SZ_TAB);
  float* hneigh = (float*)(ws + 4 * SZ_TAB);
  float* colsum = (float*)(ws + 4 * SZ_TAB + (size_t)NND * DN * 4);
  unsigned short* wtb = (unsigned short*)(ws + 4 * SZ_TAB + (size_t)NND * DN * 4 + 1024);

  // zero h_neigh + colsum (accumulated with atomics)
  hipMemsetAsync(hneigh, 0, (size_t)NND * DN * 4 + 1024, stream);

  WPrepArgs pa;
  const float* wsrc[12] = {Wq, Wk, Wm1, Wm2, Wb1, Wb2, Ww1, Ww2, Wc1, Wc2, Wn2, Wn1};
  for (int i = 0; i < 12; ++i){
    pa.w[i] = wsrc[i];
    pa.wt[i] = wtb + (size_t)i * 16384;
    pa.K[i] = (i == 11) ? 256 : 128;
  }
  prep_weights<<<dim3(128, 12), 256, 0, stream>>>(pa);

  const int NB = (NND + 63) / 64;  // 782

  node_chain<1,0,1><<<NB, 256, 0, stream>>>(coordf, pa.wt[0], bq, gq, beq, nullptr, nullptr, (void*)qt, NND);
  node_chain<1,0,1><<<NB, 256, 0, stream>>>(coordf, pa.wt[1], bk, gk, bek, nullptr, nullptr, (void*)kt, NND);
  node_chain<1,1,1><<<NB, 256, 0, stream>>>(coordf, pa.wt[2], bm1, gm, bem, pa.wt[3], bm2, (void*)mt, NND);
  node_chain<1,1,1><<<NB, 256, 0, stream>>>(coordf, pa.wt[4], bb1, gb, beb, pa.wt[5], bb2, (void*)bt, NND);
  node_chain<0,1,0><<<NB, 256, 0, stream>>>(coordf, pa.wt[8], bc1, nullptr, nullptr, pa.wt[9], nullptr,
                                            (void*)((float*)d_out + (size_t)NND * DN), NND);

  edge_kernel<<<NED / 64, 256, 0, stream>>>(qt, kt, mt, bt, pa.wt[6], pa.wt[7],
                                            bw1, gw, bew, bw2, srcI, dstI, hneigh, colsum);

  final_h<<<NB, 256, 0, stream>>>(node_feat, hneigh, colsum, pa.wt[11], bn1, pa.wt[10], bn2, (float*)d_out);
}